// Round 3
// baseline (312.620 us; speedup 1.0000x reference)
//
#include <hip/hip_runtime.h>
#include <hip/hip_bf16.h>

// MoE: N=8192 tokens, D=1024, E=8 experts, top-2 routing.
// Inputs (fp32): x[8192,1024], Wr[1024,8], br[8], W[8,1024,1024], b[8,1024]
// Output (fp32): out[8192,1024]
//
// R1: block-aggregated scatter (router atomics 16384 -> 128).
// R2: GEMM was latency-bound (MfmaUtil 11%, occupancy 22%, 75% of blocks
//     early-exit). Now: dense tile-descriptor list + split-K=2 ->
//     ~2160 uniform blocks (~8.5/CU) instead of ~1050 active among 4096.

#define NTOK 8192
#define DM   1024
#define NEXP 8
#define CAP  8192    // per-expert slot capacity (worst case)
#define MAXT 136     // max total m-tiles: 16384/128 + 7 partials <= 135
#define KSPL 2       // split-K factor

typedef __attribute__((ext_vector_type(8))) short bf16x8;
typedef __attribute__((ext_vector_type(4))) float f32x4;

__device__ __forceinline__ unsigned short f2bf(float f) {
  unsigned u = __float_as_uint(f);
  unsigned r = (u + 0x7fffu + ((u >> 16) & 1u)) >> 16;
  return (unsigned short)r;
}

__device__ __forceinline__ void gl_lds16(const void* g, void* l) {
  __builtin_amdgcn_global_load_lds(
      (const __attribute__((address_space(1))) unsigned int*)g,
      (__attribute__((address_space(3))) unsigned int*)l, 16, 0, 0);
}

// ---------------- W transpose + bf16 cast: Wt[e][h][d] = bf16(W[e][d][h]) ---
__global__ __launch_bounds__(256) void transpose_w_kernel(
    const float* __restrict__ W, unsigned short* __restrict__ Wt) {
  __shared__ float tile[64][65];  // +1 pad: conflict-free transpose
  const int e = blockIdx.z;
  const int d0 = blockIdx.y * 64, h0 = blockIdx.x * 64;
  const float* Ws = W + (size_t)e * DM * DM;
  unsigned short* Wd = Wt + (size_t)e * DM * DM;
  const int r = threadIdx.x >> 4;          // 0..15
  const int c4 = (threadIdx.x & 15) * 4;   // 0..60
#pragma unroll
  for (int k = 0; k < 4; k++) {
    int row = r + k * 16;
    float4 v = *(const float4*)(Ws + (size_t)(d0 + row) * DM + h0 + c4);
    tile[row][c4 + 0] = v.x; tile[row][c4 + 1] = v.y;
    tile[row][c4 + 2] = v.z; tile[row][c4 + 3] = v.w;
  }
  __syncthreads();
#pragma unroll
  for (int k = 0; k < 4; k++) {
    int hrow = r + k * 16;
    ushort4 o;
    o.x = f2bf(tile[c4 + 0][hrow]);
    o.y = f2bf(tile[c4 + 1][hrow]);
    o.z = f2bf(tile[c4 + 2][hrow]);
    o.w = f2bf(tile[c4 + 3][hrow]);
    *(ushort4*)(Wd + (size_t)(h0 + hrow) * DM + d0 + c4) = o;
  }
}

// ---------------- Router compute: fp32 logits, top-2, gates (atomic-free) ---
__global__ __launch_bounds__(256) void router_compute_kernel(
    const float* __restrict__ x, const float* __restrict__ Wr,
    const float* __restrict__ br, unsigned short* __restrict__ xbf,
    int4* __restrict__ topk) {
  const int tid = threadIdx.x;
  const int wave = tid >> 6, lane = tid & 63;
  const int t = blockIdx.x * 4 + wave;
  const int c0 = lane * 16;
  const float* xr = x + (size_t)t * DM + c0;

  float v[16];
#pragma unroll
  for (int i = 0; i < 4; i++) {
    float4 f = *(const float4*)(xr + i * 4);
    v[i * 4 + 0] = f.x; v[i * 4 + 1] = f.y; v[i * 4 + 2] = f.z; v[i * 4 + 3] = f.w;
  }
  union { unsigned short s[8]; uint4 q; } pk;
#pragma unroll
  for (int half = 0; half < 2; half++) {
#pragma unroll
    for (int i = 0; i < 8; i++) pk.s[i] = f2bf(v[half * 8 + i]);
    *(uint4*)(xbf + (size_t)t * DM + c0 + half * 8) = pk.q;
  }
  float p[8] = {0, 0, 0, 0, 0, 0, 0, 0};
  const float* wr = Wr + (size_t)c0 * NEXP;
#pragma unroll
  for (int i = 0; i < 16; i++) {
    float xv = v[i];
    float4 wl = *(const float4*)(wr + i * 8);
    float4 wh = *(const float4*)(wr + i * 8 + 4);
    p[0] += xv * wl.x; p[1] += xv * wl.y; p[2] += xv * wl.z; p[3] += xv * wl.w;
    p[4] += xv * wh.x; p[5] += xv * wh.y; p[6] += xv * wh.z; p[7] += xv * wh.w;
  }
#pragma unroll
  for (int off = 32; off >= 1; off >>= 1) {
#pragma unroll
    for (int e = 0; e < 8; e++) p[e] += __shfl_xor(p[e], off, 64);
  }
  if (lane == 0) {
    float lg[8];
#pragma unroll
    for (int e = 0; e < 8; e++) lg[e] = p[e] + br[e];
    float v0 = lg[0]; int i0 = 0;
#pragma unroll
    for (int e = 1; e < 8; e++) if (lg[e] > v0) { v0 = lg[e]; i0 = e; }
    float v1 = -3.4e38f; int i1 = 0;
#pragma unroll
    for (int e = 0; e < 8; e++)
      if (e != i0 && lg[e] > v1) { v1 = lg[e]; i1 = e; }
    float ee = __expf(v1 - v0);
    float g0 = 1.0f / (1.0f + ee);
    float g1 = ee / (1.0f + ee);
    int4 rec;
    rec.x = i0; rec.y = i1;
    rec.z = __float_as_int(g0); rec.w = __float_as_int(g1);
    topk[t] = rec;
  }
}

// ---------------- Scatter: block-aggregated slot assignment -----------------
__global__ __launch_bounds__(512) void scatter_kernel(
    const int4* __restrict__ topk, int* __restrict__ counts,
    int* __restrict__ tok, float* __restrict__ gat) {
  __shared__ int lcnt[NEXP], lbase[NEXP];
  const int tid = threadIdx.x;
  if (tid < NEXP) lcnt[tid] = 0;
  __syncthreads();
  const int t = blockIdx.x * 512 + tid;
  int4 r = topk[t];
  int s0 = atomicAdd(&lcnt[r.x], 1);
  int s1 = atomicAdd(&lcnt[r.y], 1);
  __syncthreads();
  if (tid < NEXP) lbase[tid] = atomicAdd(&counts[tid], lcnt[tid]);
  __syncthreads();
  int p0 = lbase[r.x] + s0;
  tok[r.x * CAP + p0] = t; gat[r.x * CAP + p0] = __int_as_float(r.z);
  int p1 = lbase[r.y] + s1;
  tok[r.y * CAP + p1] = t; gat[r.y * CAP + p1] = __int_as_float(r.w);
}

// ---------------- Tile-descriptor build: dense (expert, m-tile) list --------
__global__ __launch_bounds__(64) void build_tiles_kernel(
    const int* __restrict__ counts, int* __restrict__ desc,
    int* __restrict__ ntiles) {
  if (threadIdx.x == 0) {
    int idx = 0;
#pragma unroll
    for (int e = 0; e < NEXP; e++) {
      int nm = (counts[e] + 127) >> 7;
      for (int i = 0; i < nm; i++) desc[idx++] = (e << 16) | i;
    }
    *ntiles = idx;
  }
}

// ---------------- Routed expert GEMM + gated atomic combine -----------------
// Tile 128x128, BK=32, mfma_f32_16x16x32_bf16, 4 waves 2x2 (64x64 each).
// Grid (8 n-tiles, KSPL k-splits, MAXT desc slots); dense slots -> no idle CUs.
__global__ __launch_bounds__(256) void moe_gemm_kernel(
    const unsigned short* __restrict__ xbf, const unsigned short* __restrict__ wt,
    const float* __restrict__ bias, const int* __restrict__ counts,
    const int* __restrict__ tok, const float* __restrict__ gat,
    const int* __restrict__ desc, const int* __restrict__ ntiles,
    float* __restrict__ out) {
  const int slot = blockIdx.z;
  if (slot >= *ntiles) return;
  const int dsc = desc[slot];
  const int e = dsc >> 16;
  const int m0 = (dsc & 0xffff) * 128;
  const int cnt = counts[e];
  const int n0 = blockIdx.x * 128;
  const int kz = blockIdx.y;
  const int kbase = kz * (DM / KSPL);

  __shared__ __align__(16) unsigned short sA[128 * 32];
  __shared__ __align__(16) unsigned short sB[128 * 32];
  __shared__ int sTok[128];
  __shared__ float sGate[128];

  const int tid = threadIdx.x, wave = tid >> 6, lane = tid & 63;

  if (tid < 128) {
    int sr = m0 + tid;
    int cl = (sr < cnt) ? sr : (cnt - 1);
    sTok[tid] = tok[e * CAP + cl];
    sGate[tid] = gat[e * CAP + cl];
  }
  __syncthreads();

  // staging: wave w stages 16-row groups {w, w+4}; lane i -> row g*16+(i>>2),
  // chunk slot i&3; source chunk XOR-swizzled (2-way LDS aliasing = free).
  const int rA1 = wave * 16 + (lane >> 2);
  const int rA2 = rA1 + 64;
  const int cch = lane & 3;
  const int cg1 = (cch ^ ((rA1 >> 1) & 3)) * 8;  // elements
  const int cg2 = (cch ^ ((rA2 >> 1) & 3)) * 8;
  const unsigned short* pA1 = xbf + (size_t)sTok[rA1] * DM + kbase + cg1;
  const unsigned short* pA2 = xbf + (size_t)sTok[rA2] * DM + kbase + cg2;
  const unsigned short* wte = wt + (size_t)e * DM * DM;
  const unsigned short* pB1 = wte + (size_t)(n0 + rA1) * DM + kbase + cg1;
  const unsigned short* pB2 = wte + (size_t)(n0 + rA2) * DM + kbase + cg2;
  unsigned short* lA1 = sA + wave * 512;        // 1024B per 16-row group
  unsigned short* lA2 = sA + (wave + 4) * 512;
  unsigned short* lB1 = sB + wave * 512;
  unsigned short* lB2 = sB + (wave + 4) * 512;

  const int q = lane >> 4, ml = lane & 15;
  const int wm = (wave >> 1) * 64, wn = (wave & 1) * 64;
  int offA[4], offB[4];
#pragma unroll
  for (int i = 0; i < 4; i++) {
    int row = wm + i * 16 + ml;
    offA[i] = row * 32 + (q ^ ((row >> 1) & 3)) * 8;
    int rowb = wn + i * 16 + ml;
    offB[i] = rowb * 32 + (q ^ ((rowb >> 1) & 3)) * 8;
  }

  f32x4 acc[4][4] = {};

  for (int k0 = 0; k0 < DM / KSPL; k0 += 32) {
    gl_lds16(pA1 + k0, lA1);
    gl_lds16(pA2 + k0, lA2);
    gl_lds16(pB1 + k0, lB1);
    gl_lds16(pB2 + k0, lB2);
    __syncthreads();
    bf16x8 af[4], bf[4];
#pragma unroll
    for (int i = 0; i < 4; i++) af[i] = *(const bf16x8*)(sA + offA[i]);
#pragma unroll
    for (int i = 0; i < 4; i++) bf[i] = *(const bf16x8*)(sB + offB[i]);
#pragma unroll
    for (int mt = 0; mt < 4; mt++)
#pragma unroll
      for (int nt = 0; nt < 4; nt++)
        acc[mt][nt] = __builtin_amdgcn_mfma_f32_16x16x32_bf16(
            af[mt], bf[nt], acc[mt][nt], 0, 0, 0);
    __syncthreads();
  }

  // epilogue: out[t][col] += g * (acc + bias·[kz==0])
  const float* be = bias + (size_t)e * DM;
#pragma unroll
  for (int mt = 0; mt < 4; mt++) {
    int rbase = wm + mt * 16 + q * 4;
#pragma unroll
    for (int r = 0; r < 4; r++) {
      int row = rbase + r;
      if (m0 + row >= cnt) continue;
      int t = sTok[row];
      float g = sGate[row];
      float* orow = out + (size_t)t * DM + n0;
#pragma unroll
      for (int nt = 0; nt < 4; nt++) {
        int col = wn + nt * 16 + ml;
        float bb = (kz == 0) ? be[n0 + col] : 0.0f;
        atomicAdd(orow + col, g * (acc[mt][nt][r] + bb));
      }
    }
  }
}

extern "C" void kernel_launch(void* const* d_in, const int* in_sizes, int n_in,
                              void* d_out, int out_size, void* d_ws, size_t ws_size,
                              hipStream_t stream) {
  const float* x  = (const float*)d_in[0];
  const float* Wr = (const float*)d_in[1];
  const float* br = (const float*)d_in[2];
  const float* W  = (const float*)d_in[3];
  const float* b  = (const float*)d_in[4];
  float* out = (float*)d_out;

  // workspace layout (~32.7 MB)
  char* ws = (char*)d_ws;
  unsigned short* xbf = (unsigned short*)ws;                        // 16 MB
  unsigned short* wt  = (unsigned short*)(ws + (16u << 20));        // 16 MB
  int*   counts = (int*)(ws + (32u << 20));                         // 32 B
  int*   ntiles = (int*)(ws + (32u << 20) + 64);                    // 4 B
  int*   desc   = (int*)(ws + (32u << 20) + 128);                   // 544 B
  int*   tok    = (int*)(ws + (32u << 20) + 4096);                  // 256 KB
  float* gat    = (float*)(ws + (32u << 20) + 4096 + (256u << 10)); // 256 KB
  int4*  topk   = (int4*)(ws + (32u << 20) + 4096 + (512u << 10));  // 128 KB

  hipMemsetAsync(d_out, 0, (size_t)out_size * sizeof(float), stream);
  hipMemsetAsync(counts, 0, 128, stream);  // counts + ntiles

  transpose_w_kernel<<<dim3(16, 16, 8), 256, 0, stream>>>(W, wt);
  router_compute_kernel<<<NTOK / 4, 256, 0, stream>>>(x, Wr, br, xbf, topk);
  scatter_kernel<<<16, 512, 0, stream>>>(topk, counts, tok, gat);
  build_tiles_kernel<<<1, 64, 0, stream>>>(counts, desc, ntiles);
  moe_gemm_kernel<<<dim3(8, KSPL, MAXT), 256, 0, stream>>>(
      xbf, wt, b, counts, tok, gat, desc, ntiles, out);
}

// Round 4
// 213.954 us; speedup vs baseline: 1.4612x; 1.4612x over previous
//
#include <hip/hip_runtime.h>
#include <hip/hip_bf16.h>

// MoE: N=8192 tokens, D=1024, E=8 experts, top-2 routing.
// Inputs (fp32): x[8192,1024], Wr[1024,8], br[8], W[8,1024,1024], b[8,1024]
// Output (fp32): out[8192,1024]
//
// R1: block-aggregated scatter (router atomics 16384 -> 128).
// R2: dense tile list. R3: split-K regressed (epilogue-dominated; atomics
//     were ~40us of the 119us GEMM).
// R4: (a) atomic-free epilogue: GEMM stores bf16 acc to slot-major ybuf,
//     separate combine kernel applies gates+bias (coalesced, no RMW, no
//     out-memset). (b) two BK=32 stages per barrier (eff. BK=64): 16
//     barriers instead of 32, same proven LDS swizzle.

#define NTOK 8192
#define DM   1024
#define NEXP 8
#define CAP  8192    // per-expert slot capacity (worst case)
#define MAXT 136     // max total m-tiles

typedef __attribute__((ext_vector_type(8))) short bf16x8;
typedef __attribute__((ext_vector_type(4))) float f32x4;

__device__ __forceinline__ unsigned short f2bf(float f) {
  unsigned u = __float_as_uint(f);
  unsigned r = (u + 0x7fffu + ((u >> 16) & 1u)) >> 16;
  return (unsigned short)r;
}
__device__ __forceinline__ float bf2f(unsigned short s) {
  return __uint_as_float(((unsigned)s) << 16);
}

__device__ __forceinline__ void gl_lds16(const void* g, void* l) {
  __builtin_amdgcn_global_load_lds(
      (const __attribute__((address_space(1))) unsigned int*)g,
      (__attribute__((address_space(3))) unsigned int*)l, 16, 0, 0);
}

// ---------------- W transpose + bf16 cast: Wt[e][h][d] = bf16(W[e][d][h]) ---
__global__ __launch_bounds__(256) void transpose_w_kernel(
    const float* __restrict__ W, unsigned short* __restrict__ Wt) {
  __shared__ float tile[64][65];  // +1 pad: conflict-free transpose
  const int e = blockIdx.z;
  const int d0 = blockIdx.y * 64, h0 = blockIdx.x * 64;
  const float* Ws = W + (size_t)e * DM * DM;
  unsigned short* Wd = Wt + (size_t)e * DM * DM;
  const int r = threadIdx.x >> 4;          // 0..15
  const int c4 = (threadIdx.x & 15) * 4;   // 0..60
#pragma unroll
  for (int k = 0; k < 4; k++) {
    int row = r + k * 16;
    float4 v = *(const float4*)(Ws + (size_t)(d0 + row) * DM + h0 + c4);
    tile[row][c4 + 0] = v.x; tile[row][c4 + 1] = v.y;
    tile[row][c4 + 2] = v.z; tile[row][c4 + 3] = v.w;
  }
  __syncthreads();
#pragma unroll
  for (int k = 0; k < 4; k++) {
    int hrow = r + k * 16;
    ushort4 o;
    o.x = f2bf(tile[c4 + 0][hrow]);
    o.y = f2bf(tile[c4 + 1][hrow]);
    o.z = f2bf(tile[c4 + 2][hrow]);
    o.w = f2bf(tile[c4 + 3][hrow]);
    *(ushort4*)(Wd + (size_t)(h0 + hrow) * DM + d0 + c4) = o;
  }
}

// ---------------- Router compute: fp32 logits, top-2, gates (atomic-free) ---
__global__ __launch_bounds__(256) void router_compute_kernel(
    const float* __restrict__ x, const float* __restrict__ Wr,
    const float* __restrict__ br, unsigned short* __restrict__ xbf,
    int4* __restrict__ topk) {
  const int tid = threadIdx.x;
  const int wave = tid >> 6, lane = tid & 63;
  const int t = blockIdx.x * 4 + wave;
  const int c0 = lane * 16;
  const float* xr = x + (size_t)t * DM + c0;

  float v[16];
#pragma unroll
  for (int i = 0; i < 4; i++) {
    float4 f = *(const float4*)(xr + i * 4);
    v[i * 4 + 0] = f.x; v[i * 4 + 1] = f.y; v[i * 4 + 2] = f.z; v[i * 4 + 3] = f.w;
  }
  union { unsigned short s[8]; uint4 q; } pk;
#pragma unroll
  for (int half = 0; half < 2; half++) {
#pragma unroll
    for (int i = 0; i < 8; i++) pk.s[i] = f2bf(v[half * 8 + i]);
    *(uint4*)(xbf + (size_t)t * DM + c0 + half * 8) = pk.q;
  }
  float p[8] = {0, 0, 0, 0, 0, 0, 0, 0};
  const float* wr = Wr + (size_t)c0 * NEXP;
#pragma unroll
  for (int i = 0; i < 16; i++) {
    float xv = v[i];
    float4 wl = *(const float4*)(wr + i * 8);
    float4 wh = *(const float4*)(wr + i * 8 + 4);
    p[0] += xv * wl.x; p[1] += xv * wl.y; p[2] += xv * wl.z; p[3] += xv * wl.w;
    p[4] += xv * wh.x; p[5] += xv * wh.y; p[6] += xv * wh.z; p[7] += xv * wh.w;
  }
#pragma unroll
  for (int off = 32; off >= 1; off >>= 1) {
#pragma unroll
    for (int e = 0; e < 8; e++) p[e] += __shfl_xor(p[e], off, 64);
  }
  if (lane == 0) {
    float lg[8];
#pragma unroll
    for (int e = 0; e < 8; e++) lg[e] = p[e] + br[e];
    float v0 = lg[0]; int i0 = 0;
#pragma unroll
    for (int e = 1; e < 8; e++) if (lg[e] > v0) { v0 = lg[e]; i0 = e; }
    float v1 = -3.4e38f; int i1 = 0;
#pragma unroll
    for (int e = 0; e < 8; e++)
      if (e != i0 && lg[e] > v1) { v1 = lg[e]; i1 = e; }
    float ee = __expf(v1 - v0);
    float g0 = 1.0f / (1.0f + ee);
    float g1 = ee / (1.0f + ee);
    int4 rec;
    rec.x = i0; rec.y = i1;
    rec.z = __float_as_int(g0); rec.w = __float_as_int(g1);
    topk[t] = rec;
  }
}

// ---------------- Scatter: block-aggregated slot assignment -----------------
// Also records each token's per-expert rank (pos) for the combine gather.
__global__ __launch_bounds__(512) void scatter_kernel(
    const int4* __restrict__ topk, int* __restrict__ counts,
    int* __restrict__ tok, int2* __restrict__ pos) {
  __shared__ int lcnt[NEXP], lbase[NEXP];
  const int tid = threadIdx.x;
  if (tid < NEXP) lcnt[tid] = 0;
  __syncthreads();
  const int t = blockIdx.x * 512 + tid;
  int4 r = topk[t];
  int s0 = atomicAdd(&lcnt[r.x], 1);
  int s1 = atomicAdd(&lcnt[r.y], 1);
  __syncthreads();
  if (tid < NEXP) lbase[tid] = atomicAdd(&counts[tid], lcnt[tid]);
  __syncthreads();
  int p0 = lbase[r.x] + s0;
  int p1 = lbase[r.y] + s1;
  tok[r.x * CAP + p0] = t;
  tok[r.y * CAP + p1] = t;
  int2 pr; pr.x = p0; pr.y = p1;
  pos[t] = pr;
}

// ---------------- Tile-descriptor build + expert offsets (prefix sum) ------
__global__ __launch_bounds__(64) void build_tiles_kernel(
    const int* __restrict__ counts, int* __restrict__ desc,
    int* __restrict__ ntiles, int* __restrict__ offset) {
  if (threadIdx.x == 0) {
    int idx = 0, off = 0;
#pragma unroll
    for (int e = 0; e < NEXP; e++) {
      offset[e] = off;
      off += counts[e];
      int nm = (counts[e] + 127) >> 7;
      for (int i = 0; i < nm; i++) desc[idx++] = (e << 16) | i;
    }
    *ntiles = idx;
  }
}

// ---------------- Routed expert GEMM -> slot-major bf16 ybuf ----------------
// Tile 128x128, two BK=32 stages per barrier (eff. BK=64), 4 waves 2x2.
// Epilogue: plain bf16 stores of raw acc (gates/bias applied in combine).
__global__ __launch_bounds__(256) void moe_gemm_kernel(
    const unsigned short* __restrict__ xbf, const unsigned short* __restrict__ wt,
    const int* __restrict__ counts, const int* __restrict__ offset,
    const int* __restrict__ tok, const int* __restrict__ desc,
    const int* __restrict__ ntiles, unsigned short* __restrict__ ybuf) {
  const int slot = blockIdx.y;
  if (slot >= *ntiles) return;
  const int dsc = desc[slot];
  const int e = dsc >> 16;
  const int m0 = (dsc & 0xffff) * 128;
  const int cnt = counts[e];
  const int n0 = blockIdx.x * 128;

  __shared__ __align__(16) unsigned short sA0[128 * 32];
  __shared__ __align__(16) unsigned short sB0[128 * 32];
  __shared__ __align__(16) unsigned short sA1[128 * 32];
  __shared__ __align__(16) unsigned short sB1[128 * 32];
  __shared__ int sTok[128];

  const int tid = threadIdx.x, wave = tid >> 6, lane = tid & 63;

  if (tid < 128) {
    int sr = m0 + tid;
    int cl = (sr < cnt) ? sr : (cnt - 1);
    sTok[tid] = tok[e * CAP + cl];
  }
  __syncthreads();

  // staging: wave w stages 16-row groups {w, w+4}; lane i -> row g*16+(i>>2),
  // chunk slot i&3; source chunk XOR-swizzled (2-way LDS aliasing = free).
  const int rA1 = wave * 16 + (lane >> 2);
  const int rA2 = rA1 + 64;
  const int cch = lane & 3;
  const int cg1 = (cch ^ ((rA1 >> 1) & 3)) * 8;  // elements
  const int cg2 = (cch ^ ((rA2 >> 1) & 3)) * 8;
  const unsigned short* pA1 = xbf + (size_t)sTok[rA1] * DM + cg1;
  const unsigned short* pA2 = xbf + (size_t)sTok[rA2] * DM + cg2;
  const unsigned short* wte = wt + (size_t)e * DM * DM;
  const unsigned short* pB1 = wte + (size_t)(n0 + rA1) * DM + cg1;
  const unsigned short* pB2 = wte + (size_t)(n0 + rA2) * DM + cg2;
  const int lo1 = wave * 512, lo2 = (wave + 4) * 512;  // 1KB per 16-row group

  const int q = lane >> 4, ml = lane & 15;
  const int wm = (wave >> 1) * 64, wn = (wave & 1) * 64;
  int offA[4], offB[4];
#pragma unroll
  for (int i = 0; i < 4; i++) {
    int row = wm + i * 16 + ml;
    offA[i] = row * 32 + (q ^ ((row >> 1) & 3)) * 8;
    int rowb = wn + i * 16 + ml;
    offB[i] = rowb * 32 + (q ^ ((rowb >> 1) & 3)) * 8;
  }

  f32x4 acc[4][4] = {};

  for (int k0 = 0; k0 < DM; k0 += 64) {
    // stage both 32-wide k-halves, one barrier
    gl_lds16(pA1 + k0, sA0 + lo1);
    gl_lds16(pA2 + k0, sA0 + lo2);
    gl_lds16(pB1 + k0, sB0 + lo1);
    gl_lds16(pB2 + k0, sB0 + lo2);
    gl_lds16(pA1 + k0 + 32, sA1 + lo1);
    gl_lds16(pA2 + k0 + 32, sA1 + lo2);
    gl_lds16(pB1 + k0 + 32, sB1 + lo1);
    gl_lds16(pB2 + k0 + 32, sB1 + lo2);
    __syncthreads();
    bf16x8 af0[4], bf0[4], af1[4], bf1[4];
#pragma unroll
    for (int i = 0; i < 4; i++) {
      af0[i] = *(const bf16x8*)(sA0 + offA[i]);
      bf0[i] = *(const bf16x8*)(sB0 + offB[i]);
      af1[i] = *(const bf16x8*)(sA1 + offA[i]);
      bf1[i] = *(const bf16x8*)(sB1 + offB[i]);
    }
#pragma unroll
    for (int mt = 0; mt < 4; mt++)
#pragma unroll
      for (int nt = 0; nt < 4; nt++)
        acc[mt][nt] = __builtin_amdgcn_mfma_f32_16x16x32_bf16(
            af0[mt], bf0[nt], acc[mt][nt], 0, 0, 0);
#pragma unroll
    for (int mt = 0; mt < 4; mt++)
#pragma unroll
      for (int nt = 0; nt < 4; nt++)
        acc[mt][nt] = __builtin_amdgcn_mfma_f32_16x16x32_bf16(
            af1[mt], bf1[nt], acc[mt][nt], 0, 0, 0);
    __syncthreads();
  }

  // epilogue: plain bf16 stores of raw accumulators (slot-major)
  const int yb = offset[e] + m0;
#pragma unroll
  for (int mt = 0; mt < 4; mt++) {
    int rbase = wm + mt * 16 + q * 4;
#pragma unroll
    for (int r = 0; r < 4; r++) {
      int row = rbase + r;
      if (m0 + row >= cnt) continue;
      unsigned short* yrow = ybuf + (size_t)(yb + row) * DM + n0;
#pragma unroll
      for (int nt = 0; nt < 4; nt++) {
        yrow[wn + nt * 16 + ml] = f2bf(acc[mt][nt][r]);
      }
    }
  }
}

// ---------------- Combine: out[t] = g0*(y0+b[e0]) + g1*(y1+b[e1]) -----------
// One block per token; float4/ushort4 fully coalesced.
__global__ __launch_bounds__(256) void combine_kernel(
    const unsigned short* __restrict__ ybuf, const int4* __restrict__ topk,
    const int2* __restrict__ pos, const int* __restrict__ offset,
    const float* __restrict__ bias, float* __restrict__ out) {
  const int t = blockIdx.x;
  const int c = threadIdx.x * 4;
  int4 r = topk[t];
  int2 p = pos[t];
  float g0 = __int_as_float(r.z), g1 = __int_as_float(r.w);
  int s0 = offset[r.x] + p.x;
  int s1 = offset[r.y] + p.y;
  ushort4 ya = *(const ushort4*)(ybuf + (size_t)s0 * DM + c);
  ushort4 yb = *(const ushort4*)(ybuf + (size_t)s1 * DM + c);
  float4 b0 = *(const float4*)(bias + (size_t)r.x * DM + c);
  float4 b1 = *(const float4*)(bias + (size_t)r.y * DM + c);
  float4 o;
  o.x = g0 * (bf2f(ya.x) + b0.x) + g1 * (bf2f(yb.x) + b1.x);
  o.y = g0 * (bf2f(ya.y) + b0.y) + g1 * (bf2f(yb.y) + b1.y);
  o.z = g0 * (bf2f(ya.z) + b0.z) + g1 * (bf2f(yb.z) + b1.z);
  o.w = g0 * (bf2f(ya.w) + b0.w) + g1 * (bf2f(yb.w) + b1.w);
  *(float4*)(out + (size_t)t * DM + c) = o;
}

extern "C" void kernel_launch(void* const* d_in, const int* in_sizes, int n_in,
                              void* d_out, int out_size, void* d_ws, size_t ws_size,
                              hipStream_t stream) {
  const float* x  = (const float*)d_in[0];
  const float* Wr = (const float*)d_in[1];
  const float* br = (const float*)d_in[2];
  const float* W  = (const float*)d_in[3];
  const float* b  = (const float*)d_in[4];
  float* out = (float*)d_out;

  // workspace layout (~65.5 MB)
  char* ws = (char*)d_ws;
  unsigned short* xbf  = (unsigned short*)ws;                       // 16 MB
  unsigned short* wt   = (unsigned short*)(ws + (16u << 20));       // 16 MB
  unsigned short* ybuf = (unsigned short*)(ws + (32u << 20));       // 32 MB
  char* ctrl = ws + (64u << 20);
  int*   counts = (int*)ctrl;                                       // 32 B
  int*   ntiles = (int*)(ctrl + 64);                                // 4 B
  int*   offset = (int*)(ctrl + 128);                               // 32 B
  int*   desc   = (int*)(ctrl + 256);                               // 544 B
  int*   tok    = (int*)(ctrl + 4096);                              // 256 KB
  int2*  pos    = (int2*)(ctrl + 4096 + (256u << 10));              // 64 KB
  int4*  topk   = (int4*)(ctrl + 4096 + (320u << 10));              // 128 KB

  hipMemsetAsync(counts, 0, 128, stream);  // counts + ntiles

  transpose_w_kernel<<<dim3(16, 16, 8), 256, 0, stream>>>(W, wt);
  router_compute_kernel<<<NTOK / 4, 256, 0, stream>>>(x, Wr, br, xbf, topk);
  scatter_kernel<<<16, 512, 0, stream>>>(topk, counts, tok, pos);
  build_tiles_kernel<<<1, 64, 0, stream>>>(counts, desc, ntiles, offset);
  moe_gemm_kernel<<<dim3(8, MAXT), 256, 0, stream>>>(
      xbf, wt, counts, offset, tok, desc, ntiles, ybuf);
  combine_kernel<<<NTOK, 256, 0, stream>>>(ybuf, topk, pos, offset, b, out);
}